// Round 2
// baseline (426.906 us; speedup 1.0000x reference)
//
#include <hip/hip_runtime.h>
#include <hip/hip_bf16.h>

#define B_ 4
#define T_ 3
#define M_ 4096
#define C_ 768
#define H_ 12
#define K_ 256
#define HD_ 64
#define TM_ 4099      // T_ + M_
#define SCALE_ 0.125f // HD^-0.5

// order-preserving float->uint key (larger float -> larger key)
__device__ __forceinline__ unsigned keyf(float f) {
  unsigned u = __float_as_uint(f);
  return (u & 0x80000000u) ? ~u : (u | 0x80000000u);
}

__device__ __forceinline__ int block_excl_scan256(int v, int tid, int* sbuf) {
  sbuf[tid] = v;
  __syncthreads();
  #pragma unroll
  for (int off = 1; off < 256; off <<= 1) {
    int add = (tid >= off) ? sbuf[tid - off] : 0;
    __syncthreads();
    sbuf[tid] += add;
    __syncthreads();
  }
  int inc = sbuf[tid];
  __syncthreads();
  return inc - v;
}

// ---------- kernels ----------
__global__ void zero_out_kernel(float4* __restrict__ out, int n4) {
  int i = blockIdx.x * 256 + threadIdx.x;
  if (i < n4) out[i] = make_float4(0.f, 0.f, 0.f, 0.f);
}

// q[b,t,d] = sum_c x[b,t,c] * Wq[t,d,c] + bq[t,d]
// grid = B*T*3, block = 256 (one d per thread)
__global__ void q_kernel(const float* __restrict__ x, const float* __restrict__ Wq,
                         const float* __restrict__ bq, float* __restrict__ qbuf) {
  int blk = blockIdx.x;
  int dchunk = blk % 3;
  int bt = blk / 3;
  int t = bt % T_, b = bt / T_;
  __shared__ float xr[C_];
  const float* xrow = x + ((size_t)(b * TM_ + t)) * C_;
  for (int c = threadIdx.x; c < C_; c += 256) xr[c] = xrow[c];
  __syncthreads();
  int d = dchunk * 256 + threadIdx.x;
  const float* wrow = Wq + ((size_t)t * C_ + d) * C_;
  float acc = 0.f;
  #pragma unroll 8
  for (int c = 0; c < C_; c += 4) {
    float4 w4 = *(const float4*)(wrow + c);
    acc += xr[c] * w4.x + xr[c + 1] * w4.y + xr[c + 2] * w4.z + xr[c + 3] * w4.w;
  }
  qbuf[(size_t)(b * T_ + t) * C_ + d] = acc + bq[t * C_ + d];
}

// sprj[blk, c] = sum_{j<64} q[b,t,h*64+j] * Wkv[h*64+j, c]   (k-head projection)
// qbb[blk]    = sum_{j<64} q[b,t,h*64+j] * bkv[h*64+j]
// blk decode identical to attn_topk: t = blk%T, h = (blk/T)%H, b = blk/(T*H)
__global__ __launch_bounds__(256) void sprj_kernel(const float* __restrict__ qbuf,
                                                   const float* __restrict__ Wkv,
                                                   const float* __restrict__ bkv,
                                                   float* __restrict__ sprj,
                                                   float* __restrict__ qbb) {
  int blk = blockIdx.x;
  int t = blk % T_;
  int h = (blk / T_) % H_;
  int b = blk / (T_ * H_);
  int tid = threadIdx.x;
  __shared__ float qs[HD_];
  if (tid < HD_) qs[tid] = qbuf[((size_t)(b * T_ + t)) * C_ + h * HD_ + tid];
  __syncthreads();
  if (tid == 0) {
    float s = 0.f;
    for (int j = 0; j < HD_; ++j) s += qs[j] * bkv[h * HD_ + j];
    qbb[blk] = s;
  }
  float a0 = 0.f, a1 = 0.f, a2 = 0.f;
  for (int j = 0; j < HD_; ++j) {
    const float* wr = Wkv + ((size_t)(h * HD_ + j)) * C_;
    float qj = qs[j];
    a0 += qj * wr[tid];
    a1 += qj * wr[tid + 256];
    a2 += qj * wr[tid + 512];
  }
  float* sp = sprj + (size_t)blk * C_;
  sp[tid] = a0;
  sp[tid + 256] = a1;
  sp[tid + 512] = a2;
}

// Per (b,h,t): scores over M via feat . sprj (all f32), exact top-K via radix
// select (index-ordered ties, matching lax.top_k), softmax, then
// attn_token = (sum_k w_k feat[m_k]) @ Wv^T + bv.
// grid = B*H*T = 144, block = 256
__global__ __launch_bounds__(256) void attn_topk(
    const float* __restrict__ x, const float* __restrict__ Wkv,
    const float* __restrict__ bkv, const float* __restrict__ sprj,
    const float* __restrict__ qbb, int* __restrict__ ibuf,
    float* __restrict__ wbuf, float* __restrict__ atbuf) {
  int blk = blockIdx.x;
  int t = blk % T_;
  int h = (blk / T_) % H_;
  int b = blk / (T_ * H_);
  int tid = threadIdx.x;

  __shared__ float sc[M_];
  __shared__ float sp[C_];
  __shared__ float wfeat[C_];
  __shared__ unsigned hist[256];
  __shared__ int sbuf[256];
  __shared__ int selm[K_];
  __shared__ float wsh[K_];
  __shared__ float red[256];
  __shared__ int sh_bin, sh_rem;

  const float* sprow = sprj + (size_t)blk * C_;
  sp[tid] = sprow[tid];
  sp[tid + 256] = sprow[tid + 256];
  sp[tid + 512] = sprow[tid + 512];
  float qb = qbb[blk];
  __syncthreads();

  const float* frow_base = x + ((size_t)b * TM_ + T_) * C_; // feat rows

  // ---- scores: 16-lane groups, one row per group per pass (coalesced) ----
  {
    int grp = tid >> 4, ln = tid & 15;
    for (int m = grp; m < M_; m += 16) {
      const float4* rp = (const float4*)(frow_base + (size_t)m * C_);
      float acc = 0.f;
      #pragma unroll
      for (int it = 0; it < 12; ++it) {
        float4 f = rp[ln + it * 16];
        const float4 s = *(const float4*)&sp[(ln + it * 16) * 4];
        acc += f.x * s.x + f.y * s.y + f.z * s.z + f.w * s.w;
      }
      acc += __shfl_xor(acc, 1, 16);
      acc += __shfl_xor(acc, 2, 16);
      acc += __shfl_xor(acc, 4, 16);
      acc += __shfl_xor(acc, 8, 16);
      if (ln == 0) sc[m] = (acc + qb) * SCALE_;
    }
  }
  __syncthreads();

  // ---- radix select: find K-th largest key ----
  unsigned prefix = 0;
  int remaining = K_;
  for (int shift = 24; shift >= 0; shift -= 8) {
    hist[tid] = 0;
    __syncthreads();
    unsigned pmask = (shift == 24) ? 0u : (0xFFFFFFFFu << (shift + 8));
    for (int m = tid; m < M_; m += 256) {
      unsigned k = keyf(sc[m]);
      if ((k & pmask) == prefix) atomicAdd(&hist[(k >> shift) & 255u], 1u);
    }
    __syncthreads();
    if (tid == 0) {
      int cum = 0;
      for (int bin = 255; bin >= 0; --bin) {
        int c = (int)hist[bin];
        if (cum + c >= remaining) {
          sh_bin = bin;
          sh_rem = remaining - cum;
          break;
        }
        cum += c;
      }
    }
    __syncthreads();
    prefix |= ((unsigned)sh_bin) << shift;
    remaining = sh_rem;
    __syncthreads();
  }
  const unsigned tau = prefix;
  const int r = remaining;      // # of ==tau entries to keep (lowest indices)
  const int cgt = K_ - r;       // # of >tau entries

  // ---- compact selection in ascending-index order (deterministic) ----
  int base = tid * 16;
  int myCnt = 0, myTie = 0;
  #pragma unroll
  for (int i = 0; i < 16; i++) {
    unsigned k = keyf(sc[base + i]);
    myCnt += (k > tau);
    myTie += (k == tau);
  }
  int offs = block_excl_scan256(myCnt, tid, sbuf);
  int toffs = block_excl_scan256(myTie, tid, sbuf);
  for (int i = 0; i < 16; i++) {
    int m = base + i;
    unsigned k = keyf(sc[m]);
    if (k > tau) {
      selm[offs++] = m;
    } else if (k == tau) {
      if (toffs < r) selm[cgt + toffs] = m;
      toffs++;
    }
  }
  __syncthreads();

  // ---- softmax over the K selected ----
  int m = selm[tid];
  float val = sc[m];
  red[tid] = val;
  __syncthreads();
  for (int off = 128; off > 0; off >>= 1) {
    if (tid < off) red[tid] = fmaxf(red[tid], red[tid + off]);
    __syncthreads();
  }
  float mx = red[0];
  __syncthreads();
  float e = expf(val - mx);
  red[tid] = e;
  __syncthreads();
  for (int off = 128; off > 0; off >>= 1) {
    if (tid < off) red[tid] += red[tid + off];
    __syncthreads();
  }
  float w = e / red[0];
  wsh[tid] = w;
  ibuf[(size_t)blk * K_ + tid] = m;
  wbuf[(size_t)blk * K_ + tid] = w;
  __syncthreads();

  // ---- wfeat[c] = sum_k w_k * feat[m_k, c] ----
  {
    float wf0 = 0.f, wf1 = 0.f, wf2 = 0.f;
    for (int k = 0; k < K_; ++k) {
      float wk = wsh[k];
      const float* fr = frow_base + (size_t)selm[k] * C_;
      wf0 += wk * fr[tid];
      wf1 += wk * fr[tid + 256];
      wf2 += wk * fr[tid + 512];
    }
    wfeat[tid] = wf0;
    wfeat[tid + 256] = wf1;
    wfeat[tid + 512] = wf2;
  }
  __syncthreads();

  // ---- attn_token[h*64+r] = wfeat . Wv[row] + bv[row] ----
  {
    int grp = tid >> 4, ln = tid & 15;
    for (int rr = grp; rr < HD_; rr += 16) {
      const float4* wr = (const float4*)(Wkv + ((size_t)(C_ + h * HD_ + rr)) * C_);
      float acc = 0.f;
      #pragma unroll
      for (int it = 0; it < 12; ++it) {
        float4 wv = wr[ln + it * 16];
        const float4 fv = *(const float4*)&wfeat[(ln + it * 16) * 4];
        acc += wv.x * fv.x + wv.y * fv.y + wv.z * fv.z + wv.w * fv.w;
      }
      acc += __shfl_xor(acc, 1, 16);
      acc += __shfl_xor(acc, 2, 16);
      acc += __shfl_xor(acc, 4, 16);
      acc += __shfl_xor(acc, 8, 16);
      if (ln == 0)
        atbuf[((size_t)(b * T_ + t)) * C_ + h * HD_ + rr] =
            acc + bkv[C_ + h * HD_ + rr];
    }
  }
}

// token_output[b,t,d] = sum_c attn_token[b,t,c] * Wexp[t,d,c]
// grid = B*T*3 = 36, block 256
__global__ void token_out(const float* __restrict__ atbuf,
                          const float* __restrict__ Wexp, float* __restrict__ out) {
  int blk = blockIdx.x;
  int dchunk = blk % 3;
  int bt = blk / 3;
  int t = bt % T_, b = bt / T_;
  __shared__ float ar[C_];
  for (int c = threadIdx.x; c < C_; c += 256)
    ar[c] = atbuf[(size_t)(b * T_ + t) * C_ + c];
  __syncthreads();
  int d = dchunk * 256 + threadIdx.x;
  const float* wrow = Wexp + ((size_t)t * C_ + d) * C_;
  float acc = 0.f;
  #pragma unroll 8
  for (int c = 0; c < C_; c += 4) {
    float4 w4 = *(const float4*)(wrow + c);
    acc += ar[c] * w4.x + ar[c + 1] * w4.y + ar[c + 2] * w4.z + ar[c + 3] * w4.w;
  }
  out[((size_t)b * TM_ + t) * C_ + d] = acc;
}

// Sparse feature expansion:
// out[b, T+m, d] += w * sum_hd feat[b,m,h*64+hd] * Wexp[t,d,h*64+hd]
// grid = (B*H*T)*4 (k split into 4 chunks of 64), block 256
__global__ __launch_bounds__(256) void feature_scatter(
    const float* __restrict__ x, const float* __restrict__ Wexp,
    const int* __restrict__ ibuf, const float* __restrict__ wbuf,
    float* __restrict__ out) {
  int blk = blockIdx.x;
  int ks = blk & 3;
  int bht = blk >> 2;
  int t = bht % T_;
  int h = (bht / T_) % H_;
  int b = bht / (T_ * H_);
  int tid = threadIdx.x;

  __shared__ float fw[64][HD_]; // w_k * feat block, [kk][c]
  __shared__ int ml[64];

  const int* ip = ibuf + (size_t)bht * K_ + ks * 64;
  const float* wp = wbuf + (size_t)bht * K_ + ks * 64;
  if (tid < 64) ml[tid] = ip[tid];
  __syncthreads();

  {
    int kk = tid >> 2, cp = (tid & 3) * 16;
    int m = ml[kk];
    float wv = wp[kk];
    const float* fr = x + ((size_t)(b * TM_) + T_ + m) * C_ + h * HD_ + cp;
    #pragma unroll
    for (int j = 0; j < 16; j += 4) {
      float4 f = *(const float4*)(fr + j);
      fw[kk][cp + j + 0] = f.x * wv;
      fw[kk][cp + j + 1] = f.y * wv;
      fw[kk][cp + j + 2] = f.z * wv;
      fw[kk][cp + j + 3] = f.w * wv;
    }
  }
  __syncthreads();

  for (int dchunk = 0; dchunk < 3; ++dchunk) {
    int d = dchunk * 256 + tid;
    const float* wrow = Wexp + ((size_t)t * C_ + d) * C_ + h * HD_;
    float Wr[HD_];
    #pragma unroll
    for (int c = 0; c < HD_; c += 4) {
      float4 w4 = *(const float4*)(wrow + c);
      Wr[c] = w4.x; Wr[c + 1] = w4.y; Wr[c + 2] = w4.z; Wr[c + 3] = w4.w;
    }
    for (int kk = 0; kk < 64; ++kk) {
      float y = 0.f;
      #pragma unroll
      for (int c = 0; c < HD_; c += 4) {
        float4 f4 = *(const float4*)&fw[kk][c];
        y += Wr[c] * f4.x + Wr[c + 1] * f4.y + Wr[c + 2] * f4.z + Wr[c + 3] * f4.w;
      }
      atomicAdd(&out[((size_t)b * TM_ + T_ + ml[kk]) * C_ + d], y);
    }
  }
}

// ---------- launch ----------
extern "C" void kernel_launch(void* const* d_in, const int* in_sizes, int n_in,
                              void* d_out, int out_size, void* d_ws, size_t ws_size,
                              hipStream_t stream) {
  (void)in_sizes; (void)n_in; (void)ws_size;
  const float* x = (const float*)d_in[0];
  const float* Wq = (const float*)d_in[1];
  const float* bq = (const float*)d_in[2];
  const float* Wkv = (const float*)d_in[3];
  const float* bkv = (const float*)d_in[4];
  const float* Wexp = (const float*)d_in[5];
  float* out = (float*)d_out;

  // workspace layout (~0.8 MiB total)
  char* ws = (char*)d_ws;
  float* qbuf = (float*)ws;                         // B*T*C   = 36,864 B
  float* atbuf = (float*)(ws + 36864);              //           36,864 B
  int* ibuf = (int*)(ws + 73728);                   // 144*256 = 147,456 B
  float* wbuf = (float*)(ws + 221184);              //           147,456 B
  float* sprj = (float*)(ws + 368640);              // 144*768 = 442,368 B
  float* qbb = (float*)(ws + 811008);               //              576 B

  int n4 = out_size / 4;
  zero_out_kernel<<<(n4 + 255) / 256, 256, 0, stream>>>((float4*)out, n4);
  q_kernel<<<B_ * T_ * 3, 256, 0, stream>>>(x, Wq, bq, qbuf);
  sprj_kernel<<<B_ * H_ * T_, 256, 0, stream>>>(qbuf, Wkv, bkv, sprj, qbb);
  attn_topk<<<B_ * H_ * T_, 256, 0, stream>>>(x, Wkv, bkv, sprj, qbb, ibuf, wbuf, atbuf);
  token_out<<<B_ * T_ * 3, 256, 0, stream>>>(atbuf, Wexp, out);
  feature_scatter<<<B_ * H_ * T_ * 4, 256, 0, stream>>>(x, Wexp, ibuf, wbuf, out);
}

// Round 3
// 321.029 us; speedup vs baseline: 1.3298x; 1.3298x over previous
//
#include <hip/hip_runtime.h>
#include <hip/hip_bf16.h>

#define B_ 4
#define T_ 3
#define M_ 4096
#define C_ 768
#define H_ 12
#define K_ 256
#define HD_ 64
#define TM_ 4099      // T_ + M_
#define SCALE_ 0.125f // HD^-0.5
#define NBLK_ 144     // B*H*T, blk = b*36 + h*3 + t

// order-preserving float->uint key (larger float -> larger key)
__device__ __forceinline__ unsigned keyf(float f) {
  unsigned u = __float_as_uint(f);
  return (u & 0x80000000u) ? ~u : (u | 0x80000000u);
}

__device__ __forceinline__ int block_excl_scan256(int v, int tid, int* sbuf) {
  sbuf[tid] = v;
  __syncthreads();
  #pragma unroll
  for (int off = 1; off < 256; off <<= 1) {
    int add = (tid >= off) ? sbuf[tid - off] : 0;
    __syncthreads();
    sbuf[tid] += add;
    __syncthreads();
  }
  int inc = sbuf[tid];
  __syncthreads();
  return inc - v;
}

// ---------- kernels ----------
__global__ void zero_out_kernel(float4* __restrict__ out, int n4) {
  int i = blockIdx.x * 256 + threadIdx.x;
  if (i < n4) out[i] = make_float4(0.f, 0.f, 0.f, 0.f);
}

// q[b,t,d] = sum_c x[b,t,c] * Wq[t,d,c] + bq[t,d]
// grid = (T, 12 dchunks of 64), block = 256. Reads Wq once (4 b per block).
__global__ __launch_bounds__(256) void q_kernel(const float* __restrict__ x,
                                                const float* __restrict__ Wq,
                                                const float* __restrict__ bq,
                                                float* __restrict__ qbuf) {
  int t = blockIdx.x;
  int d0 = blockIdx.y * 64;
  int tid = threadIdx.x;
  __shared__ float ar[B_][C_];
  for (int i = tid; i < B_ * C_; i += 256) {
    int bb = i / C_, c = i % C_;
    ar[bb][c] = x[((size_t)(bb * TM_ + t)) * C_ + c];
  }
  __syncthreads();
  int grp = tid >> 4, ln = tid & 15;
  #pragma unroll
  for (int j = 0; j < 4; ++j) {
    int d = d0 + grp * 4 + j;
    const float4* wr = (const float4*)(Wq + ((size_t)t * C_ + d) * C_);
    float a0 = 0.f, a1 = 0.f, a2 = 0.f, a3 = 0.f;
    #pragma unroll
    for (int it = 0; it < 12; ++it) {
      float4 w4 = wr[ln + 16 * it];
      const float4 x0 = *(const float4*)&ar[0][(ln + 16 * it) * 4];
      const float4 x1 = *(const float4*)&ar[1][(ln + 16 * it) * 4];
      const float4 x2 = *(const float4*)&ar[2][(ln + 16 * it) * 4];
      const float4 x3 = *(const float4*)&ar[3][(ln + 16 * it) * 4];
      a0 += w4.x * x0.x + w4.y * x0.y + w4.z * x0.z + w4.w * x0.w;
      a1 += w4.x * x1.x + w4.y * x1.y + w4.z * x1.z + w4.w * x1.w;
      a2 += w4.x * x2.x + w4.y * x2.y + w4.z * x2.z + w4.w * x2.w;
      a3 += w4.x * x3.x + w4.y * x3.y + w4.z * x3.z + w4.w * x3.w;
    }
    #pragma unroll
    for (int off = 1; off < 16; off <<= 1) {
      a0 += __shfl_xor(a0, off, 16);
      a1 += __shfl_xor(a1, off, 16);
      a2 += __shfl_xor(a2, off, 16);
      a3 += __shfl_xor(a3, off, 16);
    }
    if (ln == 0) {
      float bqv = bq[t * C_ + d];
      qbuf[(size_t)(0 * T_ + t) * C_ + d] = a0 + bqv;
      qbuf[(size_t)(1 * T_ + t) * C_ + d] = a1 + bqv;
      qbuf[(size_t)(2 * T_ + t) * C_ + d] = a2 + bqv;
      qbuf[(size_t)(3 * T_ + t) * C_ + d] = a3 + bqv;
    }
  }
}

// sprj[blk, c] = sum_{j<64} q[b,t,h*64+j] * Wkv[h*64+j, c]
// qbb[blk]    = sum_{j<64} q[b,t,h*64+j] * bkv[h*64+j]
__global__ __launch_bounds__(256) void sprj_kernel(const float* __restrict__ qbuf,
                                                   const float* __restrict__ Wkv,
                                                   const float* __restrict__ bkv,
                                                   float* __restrict__ sprj,
                                                   float* __restrict__ qbb) {
  int blk = blockIdx.x;
  int t = blk % T_;
  int h = (blk / T_) % H_;
  int b = blk / (T_ * H_);
  int tid = threadIdx.x;
  __shared__ float qs[HD_];
  if (tid < HD_) qs[tid] = qbuf[((size_t)(b * T_ + t)) * C_ + h * HD_ + tid];
  __syncthreads();
  if (tid == 0) {
    float s = 0.f;
    for (int j = 0; j < HD_; ++j) s += qs[j] * bkv[h * HD_ + j];
    qbb[blk] = s;
  }
  float a0 = 0.f, a1 = 0.f, a2 = 0.f;
  for (int j = 0; j < HD_; ++j) {
    const float* wr = Wkv + ((size_t)(h * HD_ + j)) * C_;
    float qj = qs[j];
    a0 += qj * wr[tid];
    a1 += qj * wr[tid + 256];
    a2 += qj * wr[tid + 512];
  }
  float* sp = sprj + (size_t)blk * C_;
  sp[tid] = a0;
  sp[tid + 256] = a1;
  sp[tid + 512] = a2;
}

// scores: scg[blk][m] = (feat[b,m,:] . sprj[blk,:] + qbb[blk]) * SCALE
// grid = (B*T, M/64), block = 192 (12 groups of 16 lanes, one group per head).
// sprj held in registers (12 float4/lane); feat row read by all 3 waves (L1).
__global__ __launch_bounds__(192) void score_kernel(const float* __restrict__ x,
                                                    const float* __restrict__ sprj,
                                                    const float* __restrict__ qbb,
                                                    float* __restrict__ scg) {
  int bt = blockIdx.x;
  int t = bt % T_, b = bt / T_;
  int m0 = blockIdx.y * 64;
  int tid = threadIdx.x;
  int h = tid >> 4, ln = tid & 15;
  int blk = b * 36 + h * 3 + t;

  const float4* sprow = (const float4*)(sprj + (size_t)blk * C_);
  float4 sp[12];
  #pragma unroll
  for (int it = 0; it < 12; ++it) sp[it] = sprow[ln + 16 * it];
  float qb = qbb[blk];

  const float* fbase = x + ((size_t)b * TM_ + T_ + m0) * C_;
  float* srow = scg + (size_t)blk * M_ + m0;

  for (int r = 0; r < 64; ++r) {
    const float4* rp = (const float4*)(fbase + (size_t)r * C_);
    float acc = 0.f;
    #pragma unroll
    for (int it = 0; it < 12; ++it) {
      float4 f = rp[ln + 16 * it];
      acc += f.x * sp[it].x + f.y * sp[it].y + f.z * sp[it].z + f.w * sp[it].w;
    }
    acc += __shfl_xor(acc, 1, 16);
    acc += __shfl_xor(acc, 2, 16);
    acc += __shfl_xor(acc, 4, 16);
    acc += __shfl_xor(acc, 8, 16);
    if (ln == 0) srow[r] = (acc + qb) * SCALE_;
  }
}

// Per blk: exact top-K via radix select (index-ordered ties, = lax.top_k),
// softmax over selected; writes ibuf/wbuf. grid = 144, block = 256.
__global__ __launch_bounds__(256) void topk_kernel(const float* __restrict__ scg,
                                                   int* __restrict__ ibuf,
                                                   float* __restrict__ wbuf) {
  int blk = blockIdx.x;
  int tid = threadIdx.x;

  __shared__ float sc[M_];
  __shared__ unsigned hist[256];
  __shared__ int sbuf[256];
  __shared__ int selm[K_];
  __shared__ float red[256];
  __shared__ int sh_bin, sh_rem;

  const float4* srow = (const float4*)(scg + (size_t)blk * M_);
  for (int i = tid; i < M_ / 4; i += 256) ((float4*)sc)[i] = srow[i];
  __syncthreads();

  // ---- radix select: find K-th largest key ----
  unsigned prefix = 0;
  int remaining = K_;
  for (int shift = 24; shift >= 0; shift -= 8) {
    hist[tid] = 0;
    __syncthreads();
    unsigned pmask = (shift == 24) ? 0u : (0xFFFFFFFFu << (shift + 8));
    #pragma unroll 4
    for (int i = 0; i < 16; ++i) {
      unsigned k = keyf(sc[tid * 16 + i]);
      if ((k & pmask) == prefix) atomicAdd(&hist[(k >> shift) & 255u], 1u);
    }
    __syncthreads();
    int bin = 255 - tid;
    int v = (int)hist[bin];
    int cex = block_excl_scan256(v, tid, sbuf);
    if (cex < remaining && cex + v >= remaining) {
      sh_bin = bin;
      sh_rem = remaining - cex;
    }
    __syncthreads();
    prefix |= ((unsigned)sh_bin) << shift;
    remaining = sh_rem;
    __syncthreads();
  }
  const unsigned tau = prefix;
  const int r = remaining;      // # of ==tau entries to keep (lowest indices)
  const int cgt = K_ - r;       // # of >tau entries

  // ---- compact selection in ascending-index order (deterministic) ----
  int base = tid * 16;
  int myCnt = 0, myTie = 0;
  #pragma unroll
  for (int i = 0; i < 16; i++) {
    unsigned k = keyf(sc[base + i]);
    myCnt += (k > tau);
    myTie += (k == tau);
  }
  int offs = block_excl_scan256(myCnt, tid, sbuf);
  int toffs = block_excl_scan256(myTie, tid, sbuf);
  for (int i = 0; i < 16; i++) {
    int m = base + i;
    unsigned k = keyf(sc[m]);
    if (k > tau) {
      selm[offs++] = m;
    } else if (k == tau) {
      if (toffs < r) selm[cgt + toffs] = m;
      toffs++;
    }
  }
  __syncthreads();

  // ---- softmax over the K selected ----
  int m = selm[tid];
  float val = sc[m];
  red[tid] = val;
  __syncthreads();
  for (int off = 128; off > 0; off >>= 1) {
    if (tid < off) red[tid] = fmaxf(red[tid], red[tid + off]);
    __syncthreads();
  }
  float mx = red[0];
  __syncthreads();
  float e = expf(val - mx);
  red[tid] = e;
  __syncthreads();
  for (int off = 128; off > 0; off >>= 1) {
    if (tid < off) red[tid] += red[tid + off];
    __syncthreads();
  }
  ibuf[(size_t)blk * K_ + tid] = m;
  wbuf[(size_t)blk * K_ + tid] = e / red[0];
}

// wfp[blk*4+kc][c] = sum_{k in chunk} w_k * feat[m_k, c]
// grid = (144, 4), block = 256
__global__ __launch_bounds__(256) void wfeat_kernel(const float* __restrict__ x,
                                                    const int* __restrict__ ibuf,
                                                    const float* __restrict__ wbuf,
                                                    float* __restrict__ wfp) {
  int blk = blockIdx.x, kc = blockIdx.y;
  int b = blk / 36;
  int tid = threadIdx.x;
  __shared__ int ml[64];
  __shared__ float wl[64];
  if (tid < 64) {
    ml[tid] = ibuf[(size_t)blk * K_ + kc * 64 + tid];
    wl[tid] = wbuf[(size_t)blk * K_ + kc * 64 + tid];
  }
  __syncthreads();
  const float* fbase = x + ((size_t)b * TM_ + T_) * C_;
  float a0 = 0.f, a1 = 0.f, a2 = 0.f;
  for (int kk = 0; kk < 64; ++kk) {
    const float* fr = fbase + (size_t)ml[kk] * C_;
    float wv = wl[kk];
    a0 += wv * fr[tid];
    a1 += wv * fr[tid + 256];
    a2 += wv * fr[tid + 512];
  }
  float* op = wfp + ((size_t)blk * 4 + kc) * C_;
  op[tid] = a0;
  op[tid + 256] = a1;
  op[tid + 512] = a2;
}

// attn_token[b,t,h*64+rr] = (sum_kc wfp) . Wv[row] + bv[row]; grid = 144
__global__ __launch_bounds__(256) void attn_token_kernel(
    const float* __restrict__ wfp, const float* __restrict__ Wkv,
    const float* __restrict__ bkv, float* __restrict__ atbuf) {
  int blk = blockIdx.x;
  int t = blk % T_;
  int h = (blk / T_) % H_;
  int b = blk / (T_ * H_);
  int tid = threadIdx.x;
  __shared__ float wfeat[C_];
  const float* p0 = wfp + ((size_t)blk * 4) * C_;
  #pragma unroll
  for (int j = 0; j < 3; ++j) {
    int c = tid + j * 256;
    wfeat[c] = p0[c] + p0[C_ + c] + p0[2 * C_ + c] + p0[3 * C_ + c];
  }
  __syncthreads();
  int grp = tid >> 4, ln = tid & 15;
  for (int rr = grp; rr < HD_; rr += 16) {
    const float4* wr = (const float4*)(Wkv + ((size_t)(C_ + h * HD_ + rr)) * C_);
    float acc = 0.f;
    #pragma unroll
    for (int it = 0; it < 12; ++it) {
      float4 wv = wr[ln + it * 16];
      const float4 fv = *(const float4*)&wfeat[(ln + it * 16) * 4];
      acc += wv.x * fv.x + wv.y * fv.y + wv.z * fv.z + wv.w * fv.w;
    }
    acc += __shfl_xor(acc, 1, 16);
    acc += __shfl_xor(acc, 2, 16);
    acc += __shfl_xor(acc, 4, 16);
    acc += __shfl_xor(acc, 8, 16);
    if (ln == 0)
      atbuf[((size_t)(b * T_ + t)) * C_ + h * HD_ + rr] =
          acc + bkv[C_ + h * HD_ + rr];
  }
}

// token_output[b,t,d] = sum_c attn_token[b,t,c] * Wexp[t,d,c]
// grid = (T, 12 dchunks of 64), block 256. Reads Wexp once (4 b per block).
__global__ __launch_bounds__(256) void token_out(const float* __restrict__ atbuf,
                                                 const float* __restrict__ Wexp,
                                                 float* __restrict__ out) {
  int t = blockIdx.x;
  int d0 = blockIdx.y * 64;
  int tid = threadIdx.x;
  __shared__ float ar[B_][C_];
  for (int i = tid; i < B_ * C_; i += 256) {
    int bb = i / C_, c = i % C_;
    ar[bb][c] = atbuf[((size_t)(bb * T_ + t)) * C_ + c];
  }
  __syncthreads();
  int grp = tid >> 4, ln = tid & 15;
  #pragma unroll
  for (int j = 0; j < 4; ++j) {
    int d = d0 + grp * 4 + j;
    const float4* wr = (const float4*)(Wexp + ((size_t)t * C_ + d) * C_);
    float a0 = 0.f, a1 = 0.f, a2 = 0.f, a3 = 0.f;
    #pragma unroll
    for (int it = 0; it < 12; ++it) {
      float4 w4 = wr[ln + 16 * it];
      const float4 x0 = *(const float4*)&ar[0][(ln + 16 * it) * 4];
      const float4 x1 = *(const float4*)&ar[1][(ln + 16 * it) * 4];
      const float4 x2 = *(const float4*)&ar[2][(ln + 16 * it) * 4];
      const float4 x3 = *(const float4*)&ar[3][(ln + 16 * it) * 4];
      a0 += w4.x * x0.x + w4.y * x0.y + w4.z * x0.z + w4.w * x0.w;
      a1 += w4.x * x1.x + w4.y * x1.y + w4.z * x1.z + w4.w * x1.w;
      a2 += w4.x * x2.x + w4.y * x2.y + w4.z * x2.z + w4.w * x2.w;
      a3 += w4.x * x3.x + w4.y * x3.y + w4.z * x3.z + w4.w * x3.w;
    }
    #pragma unroll
    for (int off = 1; off < 16; off <<= 1) {
      a0 += __shfl_xor(a0, off, 16);
      a1 += __shfl_xor(a1, off, 16);
      a2 += __shfl_xor(a2, off, 16);
      a3 += __shfl_xor(a3, off, 16);
    }
    if (ln == 0) {
      out[((size_t)0 * TM_ + t) * C_ + d] = a0;
      out[((size_t)1 * TM_ + t) * C_ + d] = a1;
      out[((size_t)2 * TM_ + t) * C_ + d] = a2;
      out[((size_t)3 * TM_ + t) * C_ + d] = a3;
    }
  }
}

// Sparse feature expansion:
// out[b, T+m, d] += w * sum_hd feat[b,m,h*64+hd] * Wexp[t,d,h*64+hd]
// grid = (B*H*T)*4 (k split into 4 chunks of 64), block 256
__global__ __launch_bounds__(256) void feature_scatter(
    const float* __restrict__ x, const float* __restrict__ Wexp,
    const int* __restrict__ ibuf, const float* __restrict__ wbuf,
    float* __restrict__ out) {
  int blk = blockIdx.x;
  int ks = blk & 3;
  int bht = blk >> 2;
  int t = bht % T_;
  int h = (bht / T_) % H_;
  int b = bht / (T_ * H_);
  int tid = threadIdx.x;

  __shared__ float fw[64][HD_]; // w_k * feat block, [kk][c]
  __shared__ int ml[64];

  const int* ip = ibuf + (size_t)bht * K_ + ks * 64;
  const float* wp = wbuf + (size_t)bht * K_ + ks * 64;
  if (tid < 64) ml[tid] = ip[tid];
  __syncthreads();

  {
    int kk = tid >> 2, cp = (tid & 3) * 16;
    int m = ml[kk];
    float wv = wp[kk];
    const float* fr = x + ((size_t)(b * TM_) + T_ + m) * C_ + h * HD_ + cp;
    #pragma unroll
    for (int j = 0; j < 16; j += 4) {
      float4 f = *(const float4*)(fr + j);
      fw[kk][cp + j + 0] = f.x * wv;
      fw[kk][cp + j + 1] = f.y * wv;
      fw[kk][cp + j + 2] = f.z * wv;
      fw[kk][cp + j + 3] = f.w * wv;
    }
  }
  __syncthreads();

  for (int dchunk = 0; dchunk < 3; ++dchunk) {
    int d = dchunk * 256 + tid;
    const float* wrow = Wexp + ((size_t)t * C_ + d) * C_ + h * HD_;
    float Wr[HD_];
    #pragma unroll
    for (int c = 0; c < HD_; c += 4) {
      float4 w4 = *(const float4*)(wrow + c);
      Wr[c] = w4.x; Wr[c + 1] = w4.y; Wr[c + 2] = w4.z; Wr[c + 3] = w4.w;
    }
    for (int kk = 0; kk < 64; ++kk) {
      float y = 0.f;
      #pragma unroll
      for (int c = 0; c < HD_; c += 4) {
        float4 f4 = *(const float4*)&fw[kk][c];
        y += Wr[c] * f4.x + Wr[c + 1] * f4.y + Wr[c + 2] * f4.z + Wr[c + 3] * f4.w;
      }
      atomicAdd(&out[((size_t)b * TM_ + T_ + ml[kk]) * C_ + d], y);
    }
  }
}

// ---------- launch ----------
extern "C" void kernel_launch(void* const* d_in, const int* in_sizes, int n_in,
                              void* d_out, int out_size, void* d_ws, size_t ws_size,
                              hipStream_t stream) {
  (void)in_sizes; (void)n_in; (void)ws_size;
  const float* x = (const float*)d_in[0];
  const float* Wq = (const float*)d_in[1];
  const float* bq = (const float*)d_in[2];
  const float* Wkv = (const float*)d_in[3];
  const float* bkv = (const float*)d_in[4];
  const float* Wexp = (const float*)d_in[5];
  float* out = (float*)d_out;

  // workspace layout (~4.9 MiB total)
  char* ws = (char*)d_ws;
  float* qbuf = (float*)ws;                         // 36,864 B
  float* atbuf = (float*)(ws + 36864);              // 36,864 B
  int* ibuf = (int*)(ws + 73728);                   // 147,456 B
  float* wbuf = (float*)(ws + 221184);              // 147,456 B
  float* sprj = (float*)(ws + 368640);              // 442,368 B
  float* qbb = (float*)(ws + 811008);               // 576 B (pad to 1024)
  float* scg = (float*)(ws + 812032);               // 144*4096*4 = 2,359,296 B
  float* wfp = (float*)(ws + 812032 + 2359296);     // 144*4*768*4 = 1,769,472 B

  int n4 = out_size / 4;
  zero_out_kernel<<<(n4 + 255) / 256, 256, 0, stream>>>((float4*)out, n4);
  q_kernel<<<dim3(T_, 12), 256, 0, stream>>>(x, Wq, bq, qbuf);
  sprj_kernel<<<NBLK_, 256, 0, stream>>>(qbuf, Wkv, bkv, sprj, qbb);
  score_kernel<<<dim3(B_ * T_, M_ / 64), 192, 0, stream>>>(x, sprj, qbb, scg);
  topk_kernel<<<NBLK_, 256, 0, stream>>>(scg, ibuf, wbuf);
  wfeat_kernel<<<dim3(NBLK_, 4), 256, 0, stream>>>(x, ibuf, wbuf, wfp);
  attn_token_kernel<<<NBLK_, 256, 0, stream>>>(wfp, Wkv, bkv, atbuf);
  token_out<<<dim3(T_, 12), 256, 0, stream>>>(atbuf, Wexp, out);
  feature_scatter<<<NBLK_ * 4, 256, 0, stream>>>(x, Wexp, ibuf, wbuf, out);
}

// Round 4
// 255.921 us; speedup vs baseline: 1.6681x; 1.2544x over previous
//
#include <hip/hip_runtime.h>
#include <hip/hip_bf16.h>

#define B_ 4
#define T_ 3
#define M_ 4096
#define C_ 768
#define H_ 12
#define K_ 256
#define HD_ 64
#define TM_ 4099      // T_ + M_
#define SCALE_ 0.125f // HD^-0.5
#define NBLK_ 144     // B*H*T, blk = b*36 + h*3 + t

// order-preserving float->uint key (larger float -> larger key)
__device__ __forceinline__ unsigned keyf(float f) {
  unsigned u = __float_as_uint(f);
  return (u & 0x80000000u) ? ~u : (u | 0x80000000u);
}

__device__ __forceinline__ int block_excl_scan256(int v, int tid, int* sbuf) {
  sbuf[tid] = v;
  __syncthreads();
  #pragma unroll
  for (int off = 1; off < 256; off <<= 1) {
    int add = (tid >= off) ? sbuf[tid - off] : 0;
    __syncthreads();
    sbuf[tid] += add;
    __syncthreads();
  }
  int inc = sbuf[tid];
  __syncthreads();
  return inc - v;
}

// ---------- kernels ----------
__global__ void zero_out_kernel(float4* __restrict__ out, int n4) {
  int i = blockIdx.x * 256 + threadIdx.x;
  if (i < n4) out[i] = make_float4(0.f, 0.f, 0.f, 0.f);
}

// q[b,t,d] = sum_c x[b,t,c] * Wq[t,d,c] + bq[t,d]
// grid = (T, 12 dchunks of 64), block = 256. Reads Wq once (4 b per block).
__global__ __launch_bounds__(256) void q_kernel(const float* __restrict__ x,
                                                const float* __restrict__ Wq,
                                                const float* __restrict__ bq,
                                                float* __restrict__ qbuf) {
  int t = blockIdx.x;
  int d0 = blockIdx.y * 64;
  int tid = threadIdx.x;
  __shared__ float ar[B_][C_];
  for (int i = tid; i < B_ * C_; i += 256) {
    int bb = i / C_, c = i % C_;
    ar[bb][c] = x[((size_t)(bb * TM_ + t)) * C_ + c];
  }
  __syncthreads();
  int grp = tid >> 4, ln = tid & 15;
  #pragma unroll
  for (int j = 0; j < 4; ++j) {
    int d = d0 + grp * 4 + j;
    const float4* wr = (const float4*)(Wq + ((size_t)t * C_ + d) * C_);
    float a0 = 0.f, a1 = 0.f, a2 = 0.f, a3 = 0.f;
    #pragma unroll
    for (int it = 0; it < 12; ++it) {
      float4 w4 = wr[ln + 16 * it];
      const float4 x0 = *(const float4*)&ar[0][(ln + 16 * it) * 4];
      const float4 x1 = *(const float4*)&ar[1][(ln + 16 * it) * 4];
      const float4 x2 = *(const float4*)&ar[2][(ln + 16 * it) * 4];
      const float4 x3 = *(const float4*)&ar[3][(ln + 16 * it) * 4];
      a0 += w4.x * x0.x + w4.y * x0.y + w4.z * x0.z + w4.w * x0.w;
      a1 += w4.x * x1.x + w4.y * x1.y + w4.z * x1.z + w4.w * x1.w;
      a2 += w4.x * x2.x + w4.y * x2.y + w4.z * x2.z + w4.w * x2.w;
      a3 += w4.x * x3.x + w4.y * x3.y + w4.z * x3.z + w4.w * x3.w;
    }
    #pragma unroll
    for (int off = 1; off < 16; off <<= 1) {
      a0 += __shfl_xor(a0, off, 16);
      a1 += __shfl_xor(a1, off, 16);
      a2 += __shfl_xor(a2, off, 16);
      a3 += __shfl_xor(a3, off, 16);
    }
    if (ln == 0) {
      float bqv = bq[t * C_ + d];
      qbuf[(size_t)(0 * T_ + t) * C_ + d] = a0 + bqv;
      qbuf[(size_t)(1 * T_ + t) * C_ + d] = a1 + bqv;
      qbuf[(size_t)(2 * T_ + t) * C_ + d] = a2 + bqv;
      qbuf[(size_t)(3 * T_ + t) * C_ + d] = a3 + bqv;
    }
  }
}

// sprj[blk, c] = sum_{j<64} q[b,t,h*64+j] * Wkv[h*64+j, c]
// qbb[blk]    = sum_{j<64} q[b,t,h*64+j] * bkv[h*64+j]
__global__ __launch_bounds__(256) void sprj_kernel(const float* __restrict__ qbuf,
                                                   const float* __restrict__ Wkv,
                                                   const float* __restrict__ bkv,
                                                   float* __restrict__ sprj,
                                                   float* __restrict__ qbb) {
  int blk = blockIdx.x;
  int t = blk % T_;
  int h = (blk / T_) % H_;
  int b = blk / (T_ * H_);
  int tid = threadIdx.x;
  __shared__ float qs[HD_];
  if (tid < HD_) qs[tid] = qbuf[((size_t)(b * T_ + t)) * C_ + h * HD_ + tid];
  __syncthreads();
  if (tid == 0) {
    float s = 0.f;
    for (int j = 0; j < HD_; ++j) s += qs[j] * bkv[h * HD_ + j];
    qbb[blk] = s;
  }
  float a0 = 0.f, a1 = 0.f, a2 = 0.f;
  for (int j = 0; j < HD_; ++j) {
    const float* wr = Wkv + ((size_t)(h * HD_ + j)) * C_;
    float qj = qs[j];
    a0 += qj * wr[tid];
    a1 += qj * wr[tid + 256];
    a2 += qj * wr[tid + 512];
  }
  float* sp = sprj + (size_t)blk * C_;
  sp[tid] = a0;
  sp[tid + 256] = a1;
  sp[tid + 512] = a2;
}

// scores as LDS-tiled GEMM: scg[b*36+j][m] = (sprj[j,:].feat[b,m,:] + qbb)*SCALE
// grid = (B, M/64), block = 128. Thread: 2 m x 9 blk register tile.
__global__ __launch_bounds__(128) void score_kernel(const float* __restrict__ x,
                                                    const float* __restrict__ sprj,
                                                    const float* __restrict__ qbb,
                                                    float* __restrict__ scg) {
  int b = blockIdx.x;
  int m0 = blockIdx.y * 64;
  int tid = threadIdx.x;
  int ml = tid & 31, g = tid >> 5; // g in 0..3, 9 blks each

  __shared__ float fl[64][64]; // [k][m] (transposed feat chunk)
  __shared__ float sl[36][64]; // [j][k]

  float acc0[9], acc1[9];
  #pragma unroll
  for (int j = 0; j < 9; ++j) { acc0[j] = 0.f; acc1[j] = 0.f; }

  const float* fbase = x + ((size_t)b * TM_ + T_ + m0) * C_;
  const float* sbase = sprj + (size_t)b * 36 * C_;

  int r = tid >> 1, half = tid & 1;
  for (int kc = 0; kc < 12; ++kc) {
    // stage feat chunk transposed: fl[c][r] = feat[m0+r][kc*64+c]
    const float* frow = fbase + (size_t)r * C_ + kc * 64 + half * 32;
    #pragma unroll
    for (int j4 = 0; j4 < 8; ++j4) {
      float4 f4 = *(const float4*)(frow + j4 * 4);
      int c = half * 32 + j4 * 4;
      fl[c + 0][r] = f4.x;
      fl[c + 1][r] = f4.y;
      fl[c + 2][r] = f4.z;
      fl[c + 3][r] = f4.w;
    }
    // stage sprj chunk
    for (int i = tid; i < 36 * 64; i += 128) {
      int row = i >> 6, col = i & 63;
      sl[row][col] = sbase[(size_t)row * C_ + kc * 64 + col];
    }
    __syncthreads();
    #pragma unroll 4
    for (int k = 0; k < 64; ++k) {
      float2 f = *(const float2*)&fl[k][2 * ml];
      #pragma unroll
      for (int j = 0; j < 9; ++j) {
        float s = sl[g * 9 + j][k];
        acc0[j] += f.x * s;
        acc1[j] += f.y * s;
      }
    }
    __syncthreads();
  }
  #pragma unroll
  for (int j = 0; j < 9; ++j) {
    int blk = b * 36 + g * 9 + j;
    float qb = qbb[blk];
    float2 o;
    o.x = (acc0[j] + qb) * SCALE_;
    o.y = (acc1[j] + qb) * SCALE_;
    *(float2*)&scg[(size_t)blk * M_ + m0 + 2 * ml] = o;
  }
}

// Per blk: exact top-K via radix select (index-ordered ties, = lax.top_k),
// softmax over selected; writes ibuf/wbuf. grid = 144, block = 256.
__global__ __launch_bounds__(256) void topk_kernel(const float* __restrict__ scg,
                                                   int* __restrict__ ibuf,
                                                   float* __restrict__ wbuf) {
  int blk = blockIdx.x;
  int tid = threadIdx.x;

  __shared__ float sc[M_];
  __shared__ unsigned hist[256];
  __shared__ int sbuf[256];
  __shared__ int selm[K_];
  __shared__ float red[256];
  __shared__ int sh_bin, sh_rem;

  const float4* srow = (const float4*)(scg + (size_t)blk * M_);
  for (int i = tid; i < M_ / 4; i += 256) ((float4*)sc)[i] = srow[i];
  __syncthreads();

  // ---- radix select: find K-th largest key ----
  unsigned prefix = 0;
  int remaining = K_;
  for (int shift = 24; shift >= 0; shift -= 8) {
    hist[tid] = 0;
    __syncthreads();
    unsigned pmask = (shift == 24) ? 0u : (0xFFFFFFFFu << (shift + 8));
    #pragma unroll 4
    for (int i = 0; i < 16; ++i) {
      unsigned k = keyf(sc[tid * 16 + i]);
      if ((k & pmask) == prefix) atomicAdd(&hist[(k >> shift) & 255u], 1u);
    }
    __syncthreads();
    int bin = 255 - tid;
    int v = (int)hist[bin];
    int cex = block_excl_scan256(v, tid, sbuf);
    if (cex < remaining && cex + v >= remaining) {
      sh_bin = bin;
      sh_rem = remaining - cex;
    }
    __syncthreads();
    prefix |= ((unsigned)sh_bin) << shift;
    remaining = sh_rem;
    __syncthreads();
  }
  const unsigned tau = prefix;
  const int r = remaining;      // # of ==tau entries to keep (lowest indices)
  const int cgt = K_ - r;       // # of >tau entries

  // ---- compact selection in ascending-index order (deterministic) ----
  int base = tid * 16;
  int myCnt = 0, myTie = 0;
  #pragma unroll
  for (int i = 0; i < 16; i++) {
    unsigned k = keyf(sc[base + i]);
    myCnt += (k > tau);
    myTie += (k == tau);
  }
  int offs = block_excl_scan256(myCnt, tid, sbuf);
  int toffs = block_excl_scan256(myTie, tid, sbuf);
  for (int i = 0; i < 16; i++) {
    int m = base + i;
    unsigned k = keyf(sc[m]);
    if (k > tau) {
      selm[offs++] = m;
    } else if (k == tau) {
      if (toffs < r) selm[cgt + toffs] = m;
      toffs++;
    }
  }
  __syncthreads();

  // ---- softmax over the K selected ----
  int m = selm[tid];
  float val = sc[m];
  red[tid] = val;
  __syncthreads();
  for (int off = 128; off > 0; off >>= 1) {
    if (tid < off) red[tid] = fmaxf(red[tid], red[tid + off]);
    __syncthreads();
  }
  float mx = red[0];
  __syncthreads();
  float e = expf(val - mx);
  red[tid] = e;
  __syncthreads();
  for (int off = 128; off > 0; off >>= 1) {
    if (tid < off) red[tid] += red[tid + off];
    __syncthreads();
  }
  ibuf[(size_t)blk * K_ + tid] = m;
  wbuf[(size_t)blk * K_ + tid] = e / red[0];
}

// wfp[blk*4+kc][c] = sum_{k in chunk} w_k * feat[m_k, c]
// grid = (144, 4), block = 256
__global__ __launch_bounds__(256) void wfeat_kernel(const float* __restrict__ x,
                                                    const int* __restrict__ ibuf,
                                                    const float* __restrict__ wbuf,
                                                    float* __restrict__ wfp) {
  int blk = blockIdx.x, kc = blockIdx.y;
  int b = blk / 36;
  int tid = threadIdx.x;
  __shared__ int ml[64];
  __shared__ float wl[64];
  if (tid < 64) {
    ml[tid] = ibuf[(size_t)blk * K_ + kc * 64 + tid];
    wl[tid] = wbuf[(size_t)blk * K_ + kc * 64 + tid];
  }
  __syncthreads();
  const float* fbase = x + ((size_t)b * TM_ + T_) * C_;
  float a0 = 0.f, a1 = 0.f, a2 = 0.f;
  for (int kk = 0; kk < 64; ++kk) {
    const float* fr = fbase + (size_t)ml[kk] * C_;
    float wv = wl[kk];
    a0 += wv * fr[tid];
    a1 += wv * fr[tid + 256];
    a2 += wv * fr[tid + 512];
  }
  float* op = wfp + ((size_t)blk * 4 + kc) * C_;
  op[tid] = a0;
  op[tid + 256] = a1;
  op[tid + 512] = a2;
}

// attn_token[b,t,h*64+rr] = (sum_kc wfp) . Wv[row] + bv[row]; grid = 144
__global__ __launch_bounds__(256) void attn_token_kernel(
    const float* __restrict__ wfp, const float* __restrict__ Wkv,
    const float* __restrict__ bkv, float* __restrict__ atbuf) {
  int blk = blockIdx.x;
  int t = blk % T_;
  int h = (blk / T_) % H_;
  int b = blk / (T_ * H_);
  int tid = threadIdx.x;
  __shared__ float wfeat[C_];
  const float* p0 = wfp + ((size_t)blk * 4) * C_;
  #pragma unroll
  for (int j = 0; j < 3; ++j) {
    int c = tid + j * 256;
    wfeat[c] = p0[c] + p0[C_ + c] + p0[2 * C_ + c] + p0[3 * C_ + c];
  }
  __syncthreads();
  int grp = tid >> 4, ln = tid & 15;
  for (int rr = grp; rr < HD_; rr += 16) {
    const float4* wr = (const float4*)(Wkv + ((size_t)(C_ + h * HD_ + rr)) * C_);
    float acc = 0.f;
    #pragma unroll
    for (int it = 0; it < 12; ++it) {
      float4 wv = wr[ln + it * 16];
      const float4 fv = *(const float4*)&wfeat[(ln + it * 16) * 4];
      acc += wv.x * fv.x + wv.y * fv.y + wv.z * fv.z + wv.w * fv.w;
    }
    acc += __shfl_xor(acc, 1, 16);
    acc += __shfl_xor(acc, 2, 16);
    acc += __shfl_xor(acc, 4, 16);
    acc += __shfl_xor(acc, 8, 16);
    if (ln == 0)
      atbuf[((size_t)(b * T_ + t)) * C_ + h * HD_ + rr] =
          acc + bkv[C_ + h * HD_ + rr];
  }
}

// token_output[b,t,d] = sum_c attn_token[b,t,c] * Wexp[t,d,c]
// grid = (T, 12 dchunks of 64), block 256. Reads Wexp once (4 b per block).
__global__ __launch_bounds__(256) void token_out(const float* __restrict__ atbuf,
                                                 const float* __restrict__ Wexp,
                                                 float* __restrict__ out) {
  int t = blockIdx.x;
  int d0 = blockIdx.y * 64;
  int tid = threadIdx.x;
  __shared__ float ar[B_][C_];
  for (int i = tid; i < B_ * C_; i += 256) {
    int bb = i / C_, c = i % C_;
    ar[bb][c] = atbuf[((size_t)(bb * T_ + t)) * C_ + c];
  }
  __syncthreads();
  int grp = tid >> 4, ln = tid & 15;
  #pragma unroll
  for (int j = 0; j < 4; ++j) {
    int d = d0 + grp * 4 + j;
    const float4* wr = (const float4*)(Wexp + ((size_t)t * C_ + d) * C_);
    float a0 = 0.f, a1 = 0.f, a2 = 0.f, a3 = 0.f;
    #pragma unroll
    for (int it = 0; it < 12; ++it) {
      float4 w4 = wr[ln + 16 * it];
      const float4 x0 = *(const float4*)&ar[0][(ln + 16 * it) * 4];
      const float4 x1 = *(const float4*)&ar[1][(ln + 16 * it) * 4];
      const float4 x2 = *(const float4*)&ar[2][(ln + 16 * it) * 4];
      const float4 x3 = *(const float4*)&ar[3][(ln + 16 * it) * 4];
      a0 += w4.x * x0.x + w4.y * x0.y + w4.z * x0.z + w4.w * x0.w;
      a1 += w4.x * x1.x + w4.y * x1.y + w4.z * x1.z + w4.w * x1.w;
      a2 += w4.x * x2.x + w4.y * x2.y + w4.z * x2.z + w4.w * x2.w;
      a3 += w4.x * x3.x + w4.y * x3.y + w4.z * x3.z + w4.w * x3.w;
    }
    #pragma unroll
    for (int off = 1; off < 16; off <<= 1) {
      a0 += __shfl_xor(a0, off, 16);
      a1 += __shfl_xor(a1, off, 16);
      a2 += __shfl_xor(a2, off, 16);
      a3 += __shfl_xor(a3, off, 16);
    }
    if (ln == 0) {
      out[((size_t)0 * TM_ + t) * C_ + d] = a0;
      out[((size_t)1 * TM_ + t) * C_ + d] = a1;
      out[((size_t)2 * TM_ + t) * C_ + d] = a2;
      out[((size_t)3 * TM_ + t) * C_ + d] = a3;
    }
  }
}

// Sparse feature expansion:
// out[b, T+m, d] += w * sum_hd feat[b,m,h*64+hd] * Wexp[t,d,h*64+hd]
// grid = (B*H*T)*4 (k split into 4 chunks of 64), block 256
__global__ __launch_bounds__(256) void feature_scatter(
    const float* __restrict__ x, const float* __restrict__ Wexp,
    const int* __restrict__ ibuf, const float* __restrict__ wbuf,
    float* __restrict__ out) {
  int blk = blockIdx.x;
  int ks = blk & 3;
  int bht = blk >> 2;
  int t = bht % T_;
  int h = (bht / T_) % H_;
  int b = bht / (T_ * H_);
  int tid = threadIdx.x;

  __shared__ float fw[64][HD_]; // w_k * feat block, [kk][c]
  __shared__ int ml[64];

  const int* ip = ibuf + (size_t)bht * K_ + ks * 64;
  const float* wp = wbuf + (size_t)bht * K_ + ks * 64;
  if (tid < 64) ml[tid] = ip[tid];
  __syncthreads();

  {
    int kk = tid >> 2, cp = (tid & 3) * 16;
    int m = ml[kk];
    float wv = wp[kk];
    const float* fr = x + ((size_t)(b * TM_) + T_ + m) * C_ + h * HD_ + cp;
    #pragma unroll
    for (int j = 0; j < 16; j += 4) {
      float4 f = *(const float4*)(fr + j);
      fw[kk][cp + j + 0] = f.x * wv;
      fw[kk][cp + j + 1] = f.y * wv;
      fw[kk][cp + j + 2] = f.z * wv;
      fw[kk][cp + j + 3] = f.w * wv;
    }
  }
  __syncthreads();

  for (int dchunk = 0; dchunk < 3; ++dchunk) {
    int d = dchunk * 256 + tid;
    const float* wrow = Wexp + ((size_t)t * C_ + d) * C_ + h * HD_;
    float Wr[HD_];
    #pragma unroll
    for (int c = 0; c < HD_; c += 4) {
      float4 w4 = *(const float4*)(wrow + c);
      Wr[c] = w4.x; Wr[c + 1] = w4.y; Wr[c + 2] = w4.z; Wr[c + 3] = w4.w;
    }
    for (int kk = 0; kk < 64; ++kk) {
      float y = 0.f;
      #pragma unroll
      for (int c = 0; c < HD_; c += 4) {
        float4 f4 = *(const float4*)&fw[kk][c];
        y += Wr[c] * f4.x + Wr[c + 1] * f4.y + Wr[c + 2] * f4.z + Wr[c + 3] * f4.w;
      }
      atomicAdd(&out[((size_t)b * TM_ + T_ + ml[kk]) * C_ + d], y);
    }
  }
}

// ---------- launch ----------
extern "C" void kernel_launch(void* const* d_in, const int* in_sizes, int n_in,
                              void* d_out, int out_size, void* d_ws, size_t ws_size,
                              hipStream_t stream) {
  (void)in_sizes; (void)n_in; (void)ws_size;
  const float* x = (const float*)d_in[0];
  const float* Wq = (const float*)d_in[1];
  const float* bq = (const float*)d_in[2];
  const float* Wkv = (const float*)d_in[3];
  const float* bkv = (const float*)d_in[4];
  const float* Wexp = (const float*)d_in[5];
  float* out = (float*)d_out;

  // workspace layout (~4.9 MiB total)
  char* ws = (char*)d_ws;
  float* qbuf = (float*)ws;                         // 36,864 B
  float* atbuf = (float*)(ws + 36864);              // 36,864 B
  int* ibuf = (int*)(ws + 73728);                   // 147,456 B
  float* wbuf = (float*)(ws + 221184);              // 147,456 B
  float* sprj = (float*)(ws + 368640);              // 442,368 B
  float* qbb = (float*)(ws + 811008);               // 576 B (pad to 1024)
  float* scg = (float*)(ws + 812032);               // 144*4096*4 = 2,359,296 B
  float* wfp = (float*)(ws + 812032 + 2359296);     // 144*4*768*4 = 1,769,472 B

  int n4 = out_size / 4;
  zero_out_kernel<<<(n4 + 255) / 256, 256, 0, stream>>>((float4*)out, n4);
  q_kernel<<<dim3(T_, 12), 256, 0, stream>>>(x, Wq, bq, qbuf);
  sprj_kernel<<<NBLK_, 256, 0, stream>>>(qbuf, Wkv, bkv, sprj, qbb);
  score_kernel<<<dim3(B_, M_ / 64), 128, 0, stream>>>(x, sprj, qbb, scg);
  topk_kernel<<<NBLK_, 256, 0, stream>>>(scg, ibuf, wbuf);
  wfeat_kernel<<<dim3(NBLK_, 4), 256, 0, stream>>>(x, ibuf, wbuf, wfp);
  attn_token_kernel<<<NBLK_, 256, 0, stream>>>(wfp, Wkv, bkv, atbuf);
  token_out<<<dim3(T_, 12), 256, 0, stream>>>(atbuf, Wexp, out);
  feature_scatter<<<NBLK_ * 4, 256, 0, stream>>>(x, Wexp, ibuf, wbuf, out);
}